// Round 3
// baseline (171.487 us; speedup 1.0000x reference)
//
#include <hip/hip_runtime.h>
#include <hip/hip_bf16.h>

// Sobel edge detection, promote: x[32,3,512,512] f32 -> edge[32,1,512,512] f32 (0/1)
// grad_x = cross-corr with [[-1,0,1],[-2,0,2],[-1,0,1]] (depthwise, per channel)
// grad_y = cross-corr with [[-1,-2,-1],[0,0,0],[1,2,1]]
// edge = OR_c ( sqrt(gx^2+gy^2) > 0.2 )
//      = ( sqrtf( max_c (gx^2+gy^2) ) > 0.2 )   [sqrtf monotone => identical]
//
// Each thread: 4-row x 8-col output tile. Per channel, stream 6 input rows
// (rows h0-1..h0+4, cols w0-1..w0+8) with a rolling 3-row buffer of the
// separable intermediates:
//   dx[r][j] = p[j+2] - p[j]
//   sx[r][j] = p[j] + 2 p[j+1] + p[j+2]
//   gx(i,j)  = dx[i] + 2 dx[i+1] + dx[i+2]
//   gy(i,j)  = sx[i+2] - sx[i]

#define H 512
#define W 512
#define C 3
#define B 32

__global__ __launch_bounds__(256) void sobel_edge_kernel(
    const float* __restrict__ x, float* __restrict__ out) {
    // tid -> (b, hq, wq): wq in [0,64) (8-col groups), hq in [0,128) (4-row groups)
    const int tid = blockIdx.x * blockDim.x + threadIdx.x;
    const int wq = tid & 63;
    const int hq = (tid >> 6) & 127;
    const int b  = tid >> 13;          // 64*128 = 2^13 threads per image

    const int w0 = wq << 3;
    const int h0 = hq << 2;
    const float* xb = x + (size_t)b * C * H * W;

    // running max over channels of gx^2+gy^2, per output pixel
    float smax[4][8];
#pragma unroll
    for (int i = 0; i < 4; ++i)
#pragma unroll
        for (int j = 0; j < 8; ++j) smax[i][j] = 0.0f;

#pragma unroll
    for (int c = 0; c < C; ++c) {
        const float* xc = xb + (size_t)c * H * W;

        float dxb[3][8], sxb[3][8];   // rolling 3-row buffers (static indices only)

#pragma unroll
        for (int r = 0; r < 6; ++r) {
            // ---- load input row h0-1+r, cols w0-1 .. w0+8 ----
            float p[10];
            const int hh = h0 + r - 1;
            if (hh >= 0 && hh < H) {
                const float* rp = xc + (size_t)hh * W;
                const float4 m0 = *reinterpret_cast<const float4*>(rp + w0);
                const float4 m1 = *reinterpret_cast<const float4*>(rp + w0 + 4);
                p[1] = m0.x; p[2] = m0.y; p[3] = m0.z; p[4] = m0.w;
                p[5] = m1.x; p[6] = m1.y; p[7] = m1.z; p[8] = m1.w;
                p[0] = (w0 > 0)     ? rp[w0 - 1] : 0.0f;
                p[9] = (w0 + 8 < W) ? rp[w0 + 8] : 0.0f;
            } else {
#pragma unroll
                for (int k = 0; k < 10; ++k) p[k] = 0.0f;
            }

            // ---- row-wise separable intermediates into rolling slot ----
            const int rr = r % 3;      // compile-time (loop fully unrolled)
#pragma unroll
            for (int j = 0; j < 8; ++j) {
                dxb[rr][j] = p[j + 2] - p[j];
                sxb[rr][j] = p[j] + 2.0f * p[j + 1] + p[j + 2];
            }

            // ---- once 3 rows available, emit output row i = r-2 ----
            if (r >= 2) {
                const int i  = r - 2;
                const int r0 = (r - 2) % 3;
                const int r1 = (r - 1) % 3;
                const int r2 = rr;
#pragma unroll
                for (int j = 0; j < 8; ++j) {
                    const float gx = dxb[r0][j] + 2.0f * dxb[r1][j] + dxb[r2][j];
                    const float gy = sxb[r2][j] - sxb[r0][j];
                    const float s  = gx * gx + gy * gy;
                    smax[i][j] = fmaxf(smax[i][j], s);
                }
            }
        }
    }

    // ---- threshold + store (2 float4 per row) ----
    float* ob = out + ((size_t)b * H + h0) * W + w0;
#pragma unroll
    for (int i = 0; i < 4; ++i) {
        float4 o0, o1;
        o0.x = (sqrtf(smax[i][0]) > 0.2f) ? 1.0f : 0.0f;
        o0.y = (sqrtf(smax[i][1]) > 0.2f) ? 1.0f : 0.0f;
        o0.z = (sqrtf(smax[i][2]) > 0.2f) ? 1.0f : 0.0f;
        o0.w = (sqrtf(smax[i][3]) > 0.2f) ? 1.0f : 0.0f;
        o1.x = (sqrtf(smax[i][4]) > 0.2f) ? 1.0f : 0.0f;
        o1.y = (sqrtf(smax[i][5]) > 0.2f) ? 1.0f : 0.0f;
        o1.z = (sqrtf(smax[i][6]) > 0.2f) ? 1.0f : 0.0f;
        o1.w = (sqrtf(smax[i][7]) > 0.2f) ? 1.0f : 0.0f;
        float* rp = ob + (size_t)i * W;
        *reinterpret_cast<float4*>(rp)     = o0;
        *reinterpret_cast<float4*>(rp + 4) = o1;
    }
}

extern "C" void kernel_launch(void* const* d_in, const int* in_sizes, int n_in,
                              void* d_out, int out_size, void* d_ws, size_t ws_size,
                              hipStream_t stream) {
    const float* x = (const float*)d_in[0];
    float* out = (float*)d_out;
    // total threads = 32 * 128 * 64 = 262,144 -> 1024 blocks of 256
    const int total = B * (H / 4) * (W / 8);
    const int block = 256;
    const int grid = total / block;  // exact
    sobel_edge_kernel<<<grid, block, 0, stream>>>(x, out);
}